// Round 1
// 370.712 us; speedup vs baseline: 1.0412x; 1.0412x over previous
//
#include <hip/hip_runtime.h>

#define T_   2048
#define D_   256
#define N_   512
#define BTOT 16

typedef unsigned short ushortT;
typedef _Float16 f16;
typedef f16 h8 __attribute__((ext_vector_type(8)));
typedef float f4v __attribute__((ext_vector_type(4)));

// fp32 output layout (out_size = 8,421,377 floats):
//   [0, 8388608)  quantize (B,T,D) ; [8388608] diff ; [8388609, +B*T) indices
#define QN   ((size_t)BTOT*T_*D_)
#define IDX0 (QN + 1)
#define CBSTRIDE ((size_t)N_*D_)   // f16 elements per batch-slot in hi/lo

__device__ __forceinline__ float bf2f(ushortT u){
    union { unsigned int i; float f; } c; c.i = ((unsigned int)u) << 16; return c.f;
}
__device__ __forceinline__ void unp8(uint4 p, float* f){
    f[0]=bf2f((ushortT)(p.x & 0xffff)); f[1]=bf2f((ushortT)(p.x >> 16));
    f[2]=bf2f((ushortT)(p.y & 0xffff)); f[3]=bf2f((ushortT)(p.y >> 16));
    f[4]=bf2f((ushortT)(p.z & 0xffff)); f[5]=bf2f((ushortT)(p.z >> 16));
    f[6]=bf2f((ushortT)(p.w & 0xffff)); f[7]=bf2f((ushortT)(p.w >> 16));
}
__device__ __forceinline__ h8 cvt8(uint4 p){
    float f[8]; unp8(p, f);
    h8 h;
    #pragma unroll
    for (int j = 0; j < 8; j++) h[j] = (f16)f[j];
    return h;
}
__device__ __forceinline__ f4v mfma16(h8 a, h8 b, f4v c){
    return __builtin_amdgcn_mfma_f32_16x16x32_f16(a, b, c, 0, 0, 0);
}

// ---- dtype probe: bf16 vs fp32 input buffers ------------------------------
__global__ void k_probe(const ushortT* __restrict__ x, int* __restrict__ flg){
    int tid = threadIdx.x;
    ushortT u = x[tid];
    int e = (u >> 7) & 0xff;
    bool ok = (e >= 100 && e <= 140);
    unsigned long long m = __ballot(ok);
    if (tid == 0) *flg = (__popcll(m) >= 55) ? 1 : 0;
}

// ---- K1: codebook build for b in [b0, b0+BC) ------------------------------
// bf16 mode outputs: hi/lo f16 (exact 2-term split, lo scaled by 2^12) stored
// in MFMA 16x16x32 B-fragment order: elem(n,d) at
//   ((n>>4)*8 + (d>>5))*512 + ((d>>3)&3)*128 + (n&15)*8 + (d&7)
// plus e2[bl][n] = sum_d cb^2 (fp32).
// fp32 mode: original fp32 cbw layout (same ws area).
template<int BC>
__global__ __launch_bounds__(256) void k_codebook(
    const void* __restrict__ spkin, const void* __restrict__ embin,
    float* __restrict__ cbw, f16* __restrict__ hig, f16* __restrict__ logp,
    float* __restrict__ e2g, int b0, const int* __restrict__ flagp)
{
    const int isb = *flagp;
    const ushortT* ss = (const ushortT*)spkin;
    const float*   sf = (const float*)spkin;
    const ushortT* es = (const ushortT*)embin;
    const float*   ef = (const float*)embin;

    __shared__ float s2[D_ * 16];
    __shared__ float s1[D_ * 16];
    __shared__ float red[16 * D_];
    __shared__ float nrm[16];

    const int n = blockIdx.x, tid = threadIdx.x;

    for (int e = tid; e < D_ * 16; e += 256){ s2[e] = 0.f; s1[e] = 0.f; }
    __syncthreads();
    for (int e = tid; e < D_ * BC; e += 256){
        int blc = e >> 8, k = e & 255;
        int g2 = (2*BTOT + b0 + blc)*D_ + k;
        int g1 = (1*BTOT + b0 + blc)*D_ + k;
        s2[k*16 + blc] = isb ? bf2f(ss[g2]) : sf[g2];
        s1[k*16 + blc] = isb ? bf2f(ss[g1]) : sf[g1];
    }
    __syncthreads();

    const int d = tid;
    float acc[16];
    #pragma unroll
    for (int b = 0; b < 16; b++) acc[b] = 0.f;

    const size_t rb = ((size_t)n * D_ + d) * D_;

    auto inner = [&](const float* ev, int k0){
        #pragma unroll
        for (int j = 0; j < 8; j++){
            float e = ev[j];
            if (BC == 16){
                const float4* sp = (const float4*)&s2[(k0 + j) * 16];
                float4 q0 = sp[0], q1 = sp[1], q2 = sp[2], q3 = sp[3];
                acc[0]  += e*q0.x; acc[1]  += e*q0.y; acc[2]  += e*q0.z; acc[3]  += e*q0.w;
                acc[4]  += e*q1.x; acc[5]  += e*q1.y; acc[6]  += e*q1.z; acc[7]  += e*q1.w;
                acc[8]  += e*q2.x; acc[9]  += e*q2.y; acc[10] += e*q2.z; acc[11] += e*q2.w;
                acc[12] += e*q3.x; acc[13] += e*q3.y; acc[14] += e*q3.z; acc[15] += e*q3.w;
            } else {
                #pragma unroll
                for (int blc = 0; blc < BC; blc++)
                    acc[blc] += e * s2[(k0 + j)*16 + blc];
            }
        }
    };

    if (isb){
        for (int k0 = 0; k0 < D_; k0 += 8){
            uint4 p = *(const uint4*)(es + rb + k0);
            float ev[8]; unp8(p, ev);
            inner(ev, k0);
        }
    } else {
        for (int k0 = 0; k0 < D_; k0 += 8){
            float4 p0 = *(const float4*)(ef + rb + k0);
            float4 p1 = *(const float4*)(ef + rb + k0 + 4);
            float ev[8] = {p0.x,p0.y,p0.z,p0.w,p1.x,p1.y,p1.z,p1.w};
            inner(ev, k0);
        }
    }

    #pragma unroll
    for (int blc = 0; blc < BC; blc++) red[blc*D_ + d] = acc[blc]*acc[blc];
    __syncthreads();
    for (int s = 128; s > 0; s >>= 1){
        if (d < s){
            #pragma unroll
            for (int blc = 0; blc < BC; blc++) red[blc*D_ + d] += red[blc*D_ + d + s];
        }
        __syncthreads();
    }
    if (d < BC) nrm[d] = sqrtf(red[d*D_]);
    __syncthreads();

    float cbv[BC];
    #pragma unroll
    for (int blc = 0; blc < BC; blc++)
        cbv[blc] = acc[blc] / nrm[blc] + s1[d*16 + blc];

    if (!isb){
        #pragma unroll
        for (int blc = 0; blc < BC; blc++)
            cbw[((size_t)blc*N_ + n)*D_ + d] = cbv[blc];
    } else {
        // e2 reduction (red is free after the nrm barrier above)
        #pragma unroll
        for (int blc = 0; blc < BC; blc++) red[blc*D_ + d] = cbv[blc]*cbv[blc];
        __syncthreads();
        for (int s = 128; s > 0; s >>= 1){
            if (d < s){
                #pragma unroll
                for (int blc = 0; blc < BC; blc++) red[blc*D_ + d] += red[blc*D_ + d + s];
            }
            __syncthreads();
        }
        if (d < BC) e2g[(size_t)d*N_ + n] = red[d*D_];

        // exact f16 hi/lo split, staged in s2 (free after inner loop)
        f16* sh = (f16*)s2;
        #pragma unroll
        for (int blc = 0; blc < BC; blc++){
            float c = cbv[blc];
            f16 h = (f16)c;
            float r = c - (float)h;     // Sterbenz-exact
            f16 l = (f16)(r * 4096.f);  // 2^12 scale: exact, avoids f16 denorms
            sh[blc*256 + d] = h;
            sh[4096 + blc*256 + d] = l;
        }
        __syncthreads();
        // fragment-order 16B writes: group g -> ks32=g>>2, kq=g&3, d0=ks32*32+kq*8
        for (int w = tid; w < BC*32; w += 256){
            const int blc = w >> 5, g = w & 31;
            const int d0 = (g>>2)*32 + (g&3)*8;
            const size_t off = (size_t)blc*CBSTRIDE
                             + (size_t)((n>>4)*8 + (g>>2))*512
                             + (size_t)(g&3)*128 + (size_t)(n&15)*8;
            *(uint4*)(hig  + off) = *(const uint4*)(sh + blc*256 + d0);
            *(uint4*)(logp + off) = *(const uint4*)(sh + 4096 + blc*256 + d0);
        }
    }
}

// ---- K2: fused scores GEMM + argmin + gather + quantize + diff ------------
// grid Bc*16 blocks (bl, tT); 512 threads; 128 rows per block.
// bf16 path: MFMA 16x16x32_f16, A (x rows) resident in regs, B direct from
// global in fragment order (no LDS, no main-loop barriers).
__global__ __launch_bounds__(512, 2) void k_fused(
    const void* __restrict__ xin, const float* __restrict__ cbw,
    const f16* __restrict__ hig, const f16* __restrict__ logp,
    const float* __restrict__ e2g,
    float* __restrict__ outf, float* __restrict__ part,
    int blk0, const int* __restrict__ flagp)
{
    __shared__ float As[16 * 132];
    __shared__ float Bs[16 * 256];
    __shared__ float e2p[512];
    __shared__ float mv[8 * 32];
    __shared__ int   mi[8 * 32];
    __shared__ int   sfin[128];
    __shared__ float wsum[8];

    const int isb = *flagp;
    const int tid = threadIdx.x;
    const int bl = blockIdx.x >> 4, tT = blockIdx.x & 15;
    const int bg = blk0 + bl;

    if (isb){
        const ushortT* xs = (const ushortT*)xin;
        const int lane = tid & 63, wid = tid >> 6;
        const int band = wid >> 1, nh = wid & 1;     // 4 row-bands x 2 N-halves
        const int arow = lane & 15, kgrp = lane >> 4;

        // A fragments: 32 rows x K=256, bf16 -> f16 (exact)
        h8 afr[2][8];
        {
            const ushortT* xw = xs + ((size_t)bg*T_ + (size_t)tT*128 + band*32)*D_;
            #pragma unroll
            for (int rf = 0; rf < 2; rf++)
                #pragma unroll
                for (int ks = 0; ks < 8; ks++){
                    uint4 p = *(const uint4*)(xw + (size_t)(rf*16 + arow)*D_ + ks*32 + kgrp*8);
                    afr[rf][ks] = cvt8(p);
                }
        }

        const f16* hb = hig  + (size_t)bl*CBSTRIDE + (size_t)(lane*8);
        const f16* lb = logp + (size_t)bl*CBSTRIDE + (size_t)(lane*8);

        float runv[8]; int runi[8];
        #pragma unroll
        for (int i = 0; i < 8; i++){ runv[i] = 3.4e38f; runi[i] = 0x7fffffff; }

        #pragma unroll 1
        for (int c = 0; c < 8; c++){
            const int nc0 = nh*16 + c*2;            // 16-col fragment index
            f4v acch[2][2], accl[2][2];
            #pragma unroll
            for (int rf = 0; rf < 2; rf++)
                #pragma unroll
                for (int t2 = 0; t2 < 2; t2++){
                    acch[rf][t2] = (f4v){0.f,0.f,0.f,0.f};
                    accl[rf][t2] = (f4v){0.f,0.f,0.f,0.f};
                }
            const f16* hc = hb + (size_t)nc0*4096;
            const f16* lc = lb + (size_t)nc0*4096;
            #pragma unroll
            for (int ks = 0; ks < 8; ks++){
                h8 b0h = *(const h8*)(hc + ks*512);
                h8 b1h = *(const h8*)(hc + 4096 + ks*512);
                h8 b0l = *(const h8*)(lc + ks*512);
                h8 b1l = *(const h8*)(lc + 4096 + ks*512);
                #pragma unroll
                for (int rf = 0; rf < 2; rf++){
                    acch[rf][0] = mfma16(afr[rf][ks], b0h, acch[rf][0]);
                    accl[rf][0] = mfma16(afr[rf][ks], b0l, accl[rf][0]);
                    acch[rf][1] = mfma16(afr[rf][ks], b1h, acch[rf][1]);
                    accl[rf][1] = mfma16(afr[rf][ks], b1l, accl[rf][1]);
                }
            }
            // scores + running argmin (n strictly increasing per lane -> ties keep lowest n)
            #pragma unroll
            for (int t2 = 0; t2 < 2; t2++){
                const int nn = (nc0 + t2)*16 + arow;
                const float e2v = e2g[(size_t)bl*N_ + nn];
                #pragma unroll
                for (int rf = 0; rf < 2; rf++)
                    #pragma unroll
                    for (int r = 0; r < 4; r++){
                        float s = e2v - 2.f*(acch[rf][t2][r] + accl[rf][t2][r]*(1.f/4096.f));
                        int ii = rf*4 + r;
                        if (s < runv[ii]){ runv[ii] = s; runi[ii] = nn; }
                    }
            }
        }

        // argmin across the 16 col-lanes of each group (masks stay in-group)
        #pragma unroll
        for (int m = 8; m >= 1; m >>= 1){
            #pragma unroll
            for (int i = 0; i < 8; i++){
                float ov = __shfl_xor(runv[i], m);
                int   on = __shfl_xor(runi[i], m);
                if (ov < runv[i] || (ov == runv[i] && on < runi[i])){
                    runv[i] = ov; runi[i] = on;
                }
            }
        }
        if (arow == 0){
            #pragma unroll
            for (int i = 0; i < 8; i++){
                int r = (i>>2)*16 + kgrp*4 + (i&3);   // row within 32-row band
                mv[wid*32 + r] = runv[i];
                mi[wid*32 + r] = runi[i];
            }
        }
        __syncthreads();
        if (tid < 128){
            int bandt = tid >> 5, r = tid & 31;
            float v0 = mv[(bandt*2    )*32 + r]; int i0 = mi[(bandt*2    )*32 + r];
            float v1 = mv[(bandt*2 + 1)*32 + r]; int i1 = mi[(bandt*2 + 1)*32 + r];
            int nf = (v1 < v0) ? i1 : i0;            // tie -> lower half = lower n
            sfin[tid] = nf;
            outf[IDX0 + (size_t)bg*T_ + (size_t)tT*128 + tid] = (float)nf;
        }
        __syncthreads();

        // fused gather + quantize write + diff partials (wave: 16 rows, 2/iter)
        float dacc = 0.f;
        const int lh = lane >> 5, dg = lane & 31;
        #pragma unroll
        for (int it = 0; it < 8; it++){
            const int r = wid*16 + it*2 + lh;
            const int nn = sfin[r];
            const size_t off = (size_t)bl*CBSTRIDE
                             + (size_t)((nn>>4)*8 + (dg>>2))*512
                             + (size_t)(dg&3)*128 + (size_t)(nn&15)*8;
            h8 hq = *(const h8*)(hig  + off);
            h8 lq = *(const h8*)(logp + off);
            const size_t xo = ((size_t)bg*T_ + (size_t)tT*128 + r)*D_ + dg*8;
            uint4 p = *(const uint4*)(xs + xo);
            float xf8[8]; unp8(p, xf8);
            float og[8];
            #pragma unroll
            for (int j = 0; j < 8; j++){
                float q  = (float)hq[j] + (float)lq[j]*(1.f/4096.f);
                float qm = q - xf8[j];
                dacc += qm*qm;
                og[j] = 0.5f*(q + (xf8[j] + qm));
            }
            *(float4*)(outf + xo)     = make_float4(og[0],og[1],og[2],og[3]);
            *(float4*)(outf + xo + 4) = make_float4(og[4],og[5],og[6],og[7]);
        }
        #pragma unroll
        for (int o2 = 32; o2 > 0; o2 >>= 1) dacc += __shfl_down(dacc, o2, 64);
        if (lane == 0) wsum[wid] = dacc;
        __syncthreads();
        if (tid == 0){
            float t = 0.f;
            #pragma unroll
            for (int i = 0; i < 8; i++) t += wsum[i];
            atomicAdd(&part[blockIdx.x & 1023], t);
        }
    }
    else {
        // ---- fp32 fallback: VALU GEMM (original) + fused epilogue ----
        const float* xf = (const float*)xin;
        const int tx = tid & 31, ty = tid >> 5;
        const int rA = tid >> 2, qA = tid & 3;
        const int rB = tid >> 1, hB = tid & 1;
        const size_t xbase = ((size_t)bg*T_ + tT*128 + rA)*D_ + qA*4;

        float runv[8]; int runi[8];
        #pragma unroll
        for (int i = 0; i < 8; i++){ runv[i] = 3.4e38f; runi[i] = 0x7fffffff; }

        for (int nT = 0; nT < 2; nT++){
            float acc[8][8];
            #pragma unroll
            for (int i = 0; i < 8; i++)
                #pragma unroll
                for (int j = 0; j < 8; j++) acc[i][j] = 0.f;
            float e2acc = 0.f;

            const size_t bbase = ((size_t)bl*N_ + nT*256 + rB)*D_ + hB*8;

            for (int k0 = 0; k0 < D_; k0 += 16){
                float av[4];
                {
                    float4 p = *(const float4*)(xf + xbase + k0);
                    av[0]=p.x; av[1]=p.y; av[2]=p.z; av[3]=p.w;
                }
                float bv[8];
                {
                    float4 q0 = *(const float4*)(cbw + bbase + k0);
                    float4 q1 = *(const float4*)(cbw + bbase + k0 + 4);
                    bv[0]=q0.x; bv[1]=q0.y; bv[2]=q0.z; bv[3]=q0.w;
                    bv[4]=q1.x; bv[5]=q1.y; bv[6]=q1.z; bv[7]=q1.w;
                }
                #pragma unroll
                for (int j = 0; j < 8; j++) e2acc += bv[j]*bv[j];

                #pragma unroll
                for (int j = 0; j < 4; j++) As[(qA*4 + j)*132 + rA] = av[j];
                #pragma unroll
                for (int j = 0; j < 8; j++) Bs[(hB*8 + j)*256 + rB] = bv[j];
                __syncthreads();

                #pragma unroll
                for (int kl = 0; kl < 16; kl++){
                    float4 a0 = *(const float4*)&As[kl*132 + (ty<<2)];
                    float4 a1 = *(const float4*)&As[kl*132 + 64 + (ty<<2)];
                    float4 c0 = *(const float4*)&Bs[kl*256 + (tx<<2)];
                    float4 c1 = *(const float4*)&Bs[kl*256 + 128 + (tx<<2)];
                    float ar[8] = {a0.x,a0.y,a0.z,a0.w,a1.x,a1.y,a1.z,a1.w};
                    float br[8] = {c0.x,c0.y,c0.z,c0.w,c1.x,c1.y,c1.z,c1.w};
                    #pragma unroll
                    for (int i = 0; i < 8; i++)
                        #pragma unroll
                        for (int j = 0; j < 8; j++)
                            acc[i][j] += ar[i]*br[j];
                }
                __syncthreads();
            }

            e2p[rB*2 + hB] = e2acc;
            __syncthreads();

            float e2c[8];
            #pragma unroll
            for (int j = 0; j < 8; j++){
                int nl = (tx<<2) + (j&3) + ((j>>2)<<7);
                e2c[j] = e2p[nl*2] + e2p[nl*2 + 1];
            }

            #pragma unroll
            for (int i = 0; i < 8; i++){
                #pragma unroll
                for (int j = 0; j < 8; j++){
                    int ng = nT*256 + (tx<<2) + (j&3) + ((j>>2)<<7);
                    float s = e2c[j] - 2.f*acc[i][j];
                    if (s < runv[i] || (s == runv[i] && ng < runi[i])){
                        runv[i] = s; runi[i] = ng;
                    }
                }
            }
        }

        #pragma unroll
        for (int m = 16; m >= 1; m >>= 1){
            #pragma unroll
            for (int i = 0; i < 8; i++){
                float ov = __shfl_xor(runv[i], m);
                int   on = __shfl_xor(runi[i], m);
                if (ov < runv[i] || (ov == runv[i] && on < runi[i])){
                    runv[i] = ov; runi[i] = on;
                }
            }
        }
        if (tx == 0){
            #pragma unroll
            for (int i = 0; i < 8; i++){
                int row = (ty<<2) + (i&3) + ((i>>2)<<6);
                sfin[row] = runi[i];
                outf[IDX0 + (size_t)bg*T_ + (size_t)tT*128 + row] = (float)runi[i];
            }
        }
        __syncthreads();

        float dacc = 0.f;
        for (int rr = 0; rr < 128; rr += 2){
            const int row = rr + (tid >> 8);
            const int dd = tid & 255;
            const int nn = sfin[row];
            const float q = cbw[((size_t)bl*N_ + nn)*D_ + dd];
            const size_t xo = ((size_t)bg*T_ + (size_t)tT*128 + row)*D_ + dd;
            const float xv = xf[xo];
            const float qm = q - xv;
            dacc += qm*qm;
            outf[xo] = 0.5f*(q + (xv + qm));
        }
        #pragma unroll
        for (int o2 = 32; o2 > 0; o2 >>= 1) dacc += __shfl_down(dacc, o2, 64);
        if ((tid & 63) == 0) wsum[tid >> 6] = dacc;
        __syncthreads();
        if (tid == 0){
            float t = 0.f;
            #pragma unroll
            for (int i = 0; i < 8; i++) t += wsum[i];
            atomicAdd(&part[blockIdx.x & 1023], t);
        }
    }
}

// ---- K4: finalize diff (sum 1024 partials) --------------------------------
__global__ __launch_bounds__(256) void k_fin(const float* __restrict__ part,
                                             float* __restrict__ outf){
    const int tid = threadIdx.x;
    float v = part[tid] + part[tid + 256] + part[tid + 512] + part[tid + 768];
    #pragma unroll
    for (int o = 32; o > 0; o >>= 1) v += __shfl_down(v, o, 64);
    __shared__ float wsum[4];
    if ((tid & 63) == 0) wsum[tid >> 6] = v;
    __syncthreads();
    if (tid == 0)
        outf[QN] = (wsum[0] + wsum[1] + wsum[2] + wsum[3]) * (1.0f / (float)QN);
}

extern "C" void kernel_launch(void* const* d_in, const int* in_sizes, int n_in,
                              void* d_out, int out_size, void* d_ws, size_t ws_size,
                              hipStream_t stream)
{
    const void* x   = d_in[0];
    const void* spk = d_in[1];
    const void* emb = d_in[2];

    // per-chunk batch count fitting ws: cb area (hi+lo f16 == fp32 cbw) + e2 + partials + flag
    int Bc = 16;
    while (Bc > 1 && ((size_t)Bc*N_*D_*4 + (size_t)Bc*N_*4 + 4096 + 16) > ws_size) Bc >>= 1;

    char*  ws   = (char*)d_ws;
    f16*   hig  = (f16*)ws;                                      // Bc*512*256 f16
    f16*   logp = (f16*)(ws + (size_t)Bc*N_*D_*2);               // Bc*512*256 f16
    float* cbw  = (float*)ws;                                    // fp32 alias (fp32 mode)
    float* e2g  = (float*)(ws + (size_t)Bc*N_*D_*4);             // Bc*512 fp32
    float* part = (float*)(ws + (size_t)Bc*N_*D_*4 + (size_t)Bc*N_*4); // 1024 floats
    int*   flg  = (int*)((char*)part + 4096);                    // 4 B

    float* outf = (float*)d_out;

    hipMemsetAsync(part, 0, 4096, stream);
    k_probe<<<1, 64, 0, stream>>>((const ushortT*)x, flg);

    for (int b0 = 0; b0 < BTOT; b0 += Bc){
        switch (Bc){
            case 16: k_codebook<16><<<512, 256, 0, stream>>>(spk, emb, cbw, hig, logp, e2g, b0, flg); break;
            case 8:  k_codebook<8> <<<512, 256, 0, stream>>>(spk, emb, cbw, hig, logp, e2g, b0, flg); break;
            case 4:  k_codebook<4> <<<512, 256, 0, stream>>>(spk, emb, cbw, hig, logp, e2g, b0, flg); break;
            case 2:  k_codebook<2> <<<512, 256, 0, stream>>>(spk, emb, cbw, hig, logp, e2g, b0, flg); break;
            default: k_codebook<1> <<<512, 256, 0, stream>>>(spk, emb, cbw, hig, logp, e2g, b0, flg); break;
        }
        k_fused<<<Bc*16, 512, 0, stream>>>(x, cbw, hig, logp, e2g, outf, part, b0, flg);
    }
    k_fin<<<1, 256, 0, stream>>>(part, outf);
}

// Round 2
// 359.418 us; speedup vs baseline: 1.0739x; 1.0314x over previous
//
#include <hip/hip_runtime.h>

#define T_   2048
#define D_   256
#define N_   512
#define BTOT 16

typedef unsigned short ushortT;
typedef _Float16 f16;
typedef f16 h8 __attribute__((ext_vector_type(8)));
typedef float f4v __attribute__((ext_vector_type(4)));

// fp32 output layout (out_size = 8,421,377 floats):
//   [0, 8388608)  quantize (B,T,D) ; [8388608] diff ; [8388609, +B*T) indices
#define QN   ((size_t)BTOT*T_*D_)
#define IDX0 (QN + 1)
#define CBSTRIDE ((size_t)N_*D_)   // f16 elements per batch-slot in hi/lo

__device__ __forceinline__ float bf2f(ushortT u){
    union { unsigned int i; float f; } c; c.i = ((unsigned int)u) << 16; return c.f;
}
__device__ __forceinline__ void unp8(uint4 p, float* f){
    f[0]=bf2f((ushortT)(p.x & 0xffff)); f[1]=bf2f((ushortT)(p.x >> 16));
    f[2]=bf2f((ushortT)(p.y & 0xffff)); f[3]=bf2f((ushortT)(p.y >> 16));
    f[4]=bf2f((ushortT)(p.z & 0xffff)); f[5]=bf2f((ushortT)(p.z >> 16));
    f[6]=bf2f((ushortT)(p.w & 0xffff)); f[7]=bf2f((ushortT)(p.w >> 16));
}
__device__ __forceinline__ f4v mfma16(h8 a, h8 b, f4v c){
    return __builtin_amdgcn_mfma_f32_16x16x32_f16(a, b, c, 0, 0, 0);
}

// ---- dtype probe: bf16 vs fp32 input buffers ------------------------------
__global__ void k_probe(const ushortT* __restrict__ x, int* __restrict__ flg){
    int tid = threadIdx.x;
    ushortT u = x[tid];
    int e = (u >> 7) & 0xff;
    bool ok = (e >= 100 && e <= 140);
    unsigned long long m = __ballot(ok);
    if (tid == 0) *flg = (__popcll(m) >= 55) ? 1 : 0;
}

// ---- K1: codebook build for b in [b0, b0+BC) ------------------------------
// Outputs (both input dtypes): hi/lo f16 exact 2-term split (lo scaled 2^12)
// in MFMA 16x16x32 B-fragment order: elem(n,d) at
//   ((n>>4)*8 + (d>>5))*512 + ((d>>3)&3)*128 + (n&15)*8 + (d&7)
// plus e2[bl][n] = sum_d cb^2 (fp32).
template<int BC>
__global__ __launch_bounds__(256) void k_codebook(
    const void* __restrict__ spkin, const void* __restrict__ embin,
    f16* __restrict__ hig, f16* __restrict__ logp,
    float* __restrict__ e2g, int b0, const int* __restrict__ flagp)
{
    const int isb = *flagp;
    const ushortT* ss = (const ushortT*)spkin;
    const float*   sf = (const float*)spkin;
    const ushortT* es = (const ushortT*)embin;
    const float*   ef = (const float*)embin;

    __shared__ float s2[D_ * 16];
    __shared__ float s1[D_ * 16];
    __shared__ float red[16 * D_];
    __shared__ float nrm[16];

    const int n = blockIdx.x, tid = threadIdx.x;

    for (int e = tid; e < D_ * 16; e += 256){ s2[e] = 0.f; s1[e] = 0.f; }
    __syncthreads();
    for (int e = tid; e < D_ * BC; e += 256){
        int blc = e >> 8, k = e & 255;
        int g2 = (2*BTOT + b0 + blc)*D_ + k;
        int g1 = (1*BTOT + b0 + blc)*D_ + k;
        s2[k*16 + blc] = isb ? bf2f(ss[g2]) : sf[g2];
        s1[k*16 + blc] = isb ? bf2f(ss[g1]) : sf[g1];
    }
    __syncthreads();

    const int d = tid;
    float acc[16];
    #pragma unroll
    for (int b = 0; b < 16; b++) acc[b] = 0.f;

    const size_t rb = ((size_t)n * D_ + d) * D_;

    auto inner = [&](const float* ev, int k0){
        #pragma unroll
        for (int j = 0; j < 8; j++){
            float e = ev[j];
            if (BC == 16){
                const float4* sp = (const float4*)&s2[(k0 + j) * 16];
                float4 q0 = sp[0], q1 = sp[1], q2 = sp[2], q3 = sp[3];
                acc[0]  += e*q0.x; acc[1]  += e*q0.y; acc[2]  += e*q0.z; acc[3]  += e*q0.w;
                acc[4]  += e*q1.x; acc[5]  += e*q1.y; acc[6]  += e*q1.z; acc[7]  += e*q1.w;
                acc[8]  += e*q2.x; acc[9]  += e*q2.y; acc[10] += e*q2.z; acc[11] += e*q2.w;
                acc[12] += e*q3.x; acc[13] += e*q3.y; acc[14] += e*q3.z; acc[15] += e*q3.w;
            } else {
                #pragma unroll
                for (int blc = 0; blc < BC; blc++)
                    acc[blc] += e * s2[(k0 + j)*16 + blc];
            }
        }
    };

    if (isb){
        for (int k0 = 0; k0 < D_; k0 += 8){
            uint4 p = *(const uint4*)(es + rb + k0);
            float ev[8]; unp8(p, ev);
            inner(ev, k0);
        }
    } else {
        for (int k0 = 0; k0 < D_; k0 += 8){
            float4 p0 = *(const float4*)(ef + rb + k0);
            float4 p1 = *(const float4*)(ef + rb + k0 + 4);
            float ev[8] = {p0.x,p0.y,p0.z,p0.w,p1.x,p1.y,p1.z,p1.w};
            inner(ev, k0);
        }
    }

    #pragma unroll
    for (int blc = 0; blc < BC; blc++) red[blc*D_ + d] = acc[blc]*acc[blc];
    __syncthreads();
    for (int s = 128; s > 0; s >>= 1){
        if (d < s){
            #pragma unroll
            for (int blc = 0; blc < BC; blc++) red[blc*D_ + d] += red[blc*D_ + d + s];
        }
        __syncthreads();
    }
    if (d < BC) nrm[d] = sqrtf(red[d*D_]);
    __syncthreads();

    float cbv[BC];
    #pragma unroll
    for (int blc = 0; blc < BC; blc++)
        cbv[blc] = acc[blc] / nrm[blc] + s1[d*16 + blc];

    // e2 reduction (red free after nrm barrier)
    #pragma unroll
    for (int blc = 0; blc < BC; blc++) red[blc*D_ + d] = cbv[blc]*cbv[blc];
    __syncthreads();
    for (int s = 128; s > 0; s >>= 1){
        if (d < s){
            #pragma unroll
            for (int blc = 0; blc < BC; blc++) red[blc*D_ + d] += red[blc*D_ + d + s];
        }
        __syncthreads();
    }
    if (d < BC) e2g[(size_t)d*N_ + n] = red[d*D_];

    // exact f16 hi/lo split staged in s2 (free after inner loop)
    f16* sh = (f16*)s2;
    #pragma unroll
    for (int blc = 0; blc < BC; blc++){
        float c = cbv[blc];
        f16 h = (f16)c;
        float r = c - (float)h;     // exact in fp32
        f16 l = (f16)(r * 4096.f);  // 2^12 scale: exact, no f16 denorms
        sh[blc*256 + d] = h;
        sh[4096 + blc*256 + d] = l;
    }
    __syncthreads();
    // fragment-order 16B writes
    for (int w = tid; w < BC*32; w += 256){
        const int blc = w >> 5, g = w & 31;
        const int d0 = (g>>2)*32 + (g&3)*8;
        const size_t off = (size_t)blc*CBSTRIDE
                         + (size_t)((n>>4)*8 + (g>>2))*512
                         + (size_t)(g&3)*128 + (size_t)(n&15)*8;
        *(uint4*)(hig  + off) = *(const uint4*)(sh + blc*256 + d0);
        *(uint4*)(logp + off) = *(const uint4*)(sh + 4096 + blc*256 + d0);
    }
}

// ---- K2: fused scores GEMM (MFMA, f16 hi/lo splits) + argmin + gather -----
// grid Bc*32 blocks (bl, tT); 512 threads = 8 waves = 4 row-bands x 2 N-halves.
// 64 rows per block. A (x rows) resident in regs as exact hi/lo f16 split;
// B streamed from global in fragment order. No LDS in main loop.
__global__ __launch_bounds__(512, 2) void k_fused(
    const void* __restrict__ xin,
    const f16* __restrict__ hig, const f16* __restrict__ logp,
    const float* __restrict__ e2g,
    float* __restrict__ outf, float* __restrict__ part,
    int blk0, const int* __restrict__ flagp)
{
    __shared__ float mv[8 * 16];
    __shared__ int   mi[8 * 16];
    __shared__ int   sfin[64];
    __shared__ float wsum[8];

    const int isb = *flagp;
    const int tid = threadIdx.x;
    const int bl = blockIdx.x >> 5, tT = blockIdx.x & 31;
    const int bg = blk0 + bl;
    const int lane = tid & 63, wid = tid >> 6;
    const int band = wid >> 1, nh = wid & 1;
    const int arow = lane & 15, kgrp = lane >> 4;

    const ushortT* xs = (const ushortT*)xin;
    const float*   xf = (const float*)xin;

    // ---- A fragments: 16 rows x K=256, exact hi/lo f16 split --------------
    h8 ah[8], al[8];
    {
        const size_t rowbase = ((size_t)bg*T_ + (size_t)tT*64 + band*16 + arow) * D_;
        #pragma unroll
        for (int ks = 0; ks < 8; ks++){
            float f[8];
            const size_t o = rowbase + ks*32 + kgrp*8;
            if (isb){
                uint4 p = *(const uint4*)(xs + o);
                unp8(p, f);
            } else {
                float4 p0 = *(const float4*)(xf + o);
                float4 p1 = *(const float4*)(xf + o + 4);
                f[0]=p0.x; f[1]=p0.y; f[2]=p0.z; f[3]=p0.w;
                f[4]=p1.x; f[5]=p1.y; f[6]=p1.z; f[7]=p1.w;
            }
            h8 h, l;
            #pragma unroll
            for (int j = 0; j < 8; j++){
                f16 hh = (f16)f[j];
                h[j] = hh;
                l[j] = (f16)((f[j] - (float)hh) * 4096.f);  // exact residual
            }
            ah[ks] = h; al[ks] = l;
        }
    }

    const f16* hb = hig  + (size_t)bl*CBSTRIDE + (size_t)(lane*8);
    const f16* lb = logp + (size_t)bl*CBSTRIDE + (size_t)(lane*8);

    float runv[4]; int runi[4];
    #pragma unroll
    for (int i = 0; i < 4; i++){ runv[i] = 3.4e38f; runi[i] = 0x7fffffff; }

    #pragma unroll 1
    for (int c = 0; c < 8; c++){
        const int nc0 = nh*16 + c*2;                // 16-col fragment index
        f4v acch[2], accm[2], accl[2];
        #pragma unroll
        for (int t2 = 0; t2 < 2; t2++){
            acch[t2] = (f4v){0.f,0.f,0.f,0.f};
            accm[t2] = (f4v){0.f,0.f,0.f,0.f};
            accl[t2] = (f4v){0.f,0.f,0.f,0.f};
        }
        const f16* hc = hb + (size_t)nc0*4096;
        const f16* lc = lb + (size_t)nc0*4096;
        #pragma unroll
        for (int ks = 0; ks < 8; ks++){
            h8 b0h = *(const h8*)(hc + ks*512);
            h8 b1h = *(const h8*)(hc + 4096 + ks*512);
            h8 b0l = *(const h8*)(lc + ks*512);
            h8 b1l = *(const h8*)(lc + 4096 + ks*512);
            acch[0] = mfma16(ah[ks], b0h, acch[0]);
            accm[0] = mfma16(ah[ks], b0l, accm[0]);
            accm[0] = mfma16(al[ks], b0h, accm[0]);
            accl[0] = mfma16(al[ks], b0l, accl[0]);
            acch[1] = mfma16(ah[ks], b1h, acch[1]);
            accm[1] = mfma16(ah[ks], b1l, accm[1]);
            accm[1] = mfma16(al[ks], b1h, accm[1]);
            accl[1] = mfma16(al[ks], b1l, accl[1]);
        }
        // scores: lane owns rows m = kgrp*4 + r, col n = (nc0+t2)*16 + arow
        #pragma unroll
        for (int t2 = 0; t2 < 2; t2++){
            const int nn = (nc0 + t2)*16 + arow;
            const float e2v = e2g[(size_t)bl*N_ + nn];
            #pragma unroll
            for (int r = 0; r < 4; r++){
                float dot = acch[t2][r] + accm[t2][r]*(1.f/4096.f)
                          + accl[t2][r]*(1.f/16777216.f);
                float s = e2v - 2.f*dot;
                if (s < runv[r]){ runv[r] = s; runi[r] = nn; }  // n increasing: ties keep low n
            }
        }
    }

    // argmin across the 16 arow-lanes (xor masks stay within the 16-group)
    #pragma unroll
    for (int m = 8; m >= 1; m >>= 1){
        #pragma unroll
        for (int r = 0; r < 4; r++){
            float ov = __shfl_xor(runv[r], m);
            int   on = __shfl_xor(runi[r], m);
            if (ov < runv[r] || (ov == runv[r] && on < runi[r])){
                runv[r] = ov; runi[r] = on;
            }
        }
    }
    if (arow == 0){
        #pragma unroll
        for (int r = 0; r < 4; r++){
            mv[wid*16 + kgrp*4 + r] = runv[r];
            mi[wid*16 + kgrp*4 + r] = runi[r];
        }
    }
    __syncthreads();
    if (tid < 64){
        const int bandt = tid >> 4, rl = tid & 15;
        float v0 = mv[(bandt*2    )*16 + rl]; int i0 = mi[(bandt*2    )*16 + rl];
        float v1 = mv[(bandt*2 + 1)*16 + rl]; int i1 = mi[(bandt*2 + 1)*16 + rl];
        int nf = (v1 < v0) ? i1 : i0;          // strict: nh=0 wins ties (lower n)
        sfin[tid] = nf;
        outf[IDX0 + (size_t)bg*T_ + (size_t)tT*64 + tid] = (float)nf;
    }
    __syncthreads();

    // ---- fused gather + quantize write + diff partials --------------------
    // thread: row r = tid>>3 (64 rows), d-octant oct = tid&7 (32 d each)
    float dacc = 0.f;
    {
        const int r = tid >> 3, oct = tid & 7;
        const int nn = sfin[r];
        const size_t fb = (size_t)bl*CBSTRIDE
                        + (size_t)((nn>>4)*8 + oct)*512 + (size_t)(nn&15)*8;
        const size_t xo0 = ((size_t)bg*T_ + (size_t)tT*64 + r)*D_ + oct*32;
        #pragma unroll
        for (int q = 0; q < 4; q++){
            h8 hq = *(const h8*)(hig  + fb + q*128);
            h8 lq = *(const h8*)(logp + fb + q*128);
            float xv[8];
            if (isb){
                uint4 p = *(const uint4*)(xs + xo0 + q*8);
                unp8(p, xv);
            } else {
                float4 p0 = *(const float4*)(xf + xo0 + q*8);
                float4 p1 = *(const float4*)(xf + xo0 + q*8 + 4);
                xv[0]=p0.x; xv[1]=p0.y; xv[2]=p0.z; xv[3]=p0.w;
                xv[4]=p1.x; xv[5]=p1.y; xv[6]=p1.z; xv[7]=p1.w;
            }
            float og[8];
            #pragma unroll
            for (int j = 0; j < 8; j++){
                float qv = (float)hq[j] + (float)lq[j]*(1.f/4096.f);
                float qm = qv - xv[j];
                dacc += qm*qm;
                og[j] = 0.5f*(qv + (xv[j] + qm));
            }
            *(float4*)(outf + xo0 + q*8)     = make_float4(og[0],og[1],og[2],og[3]);
            *(float4*)(outf + xo0 + q*8 + 4) = make_float4(og[4],og[5],og[6],og[7]);
        }
    }
    #pragma unroll
    for (int o2 = 32; o2 > 0; o2 >>= 1) dacc += __shfl_down(dacc, o2, 64);
    if (lane == 0) wsum[wid] = dacc;
    __syncthreads();
    if (tid == 0){
        float t = 0.f;
        #pragma unroll
        for (int i = 0; i < 8; i++) t += wsum[i];
        atomicAdd(&part[blockIdx.x & 1023], t);
    }
}

// ---- K4: finalize diff (sum 1024 partials) --------------------------------
__global__ __launch_bounds__(256) void k_fin(const float* __restrict__ part,
                                             float* __restrict__ outf){
    const int tid = threadIdx.x;
    float v = part[tid] + part[tid + 256] + part[tid + 512] + part[tid + 768];
    #pragma unroll
    for (int o = 32; o > 0; o >>= 1) v += __shfl_down(v, o, 64);
    __shared__ float wsum[4];
    if ((tid & 63) == 0) wsum[tid >> 6] = v;
    __syncthreads();
    if (tid == 0)
        outf[QN] = (wsum[0] + wsum[1] + wsum[2] + wsum[3]) * (1.0f / (float)QN);
}

extern "C" void kernel_launch(void* const* d_in, const int* in_sizes, int n_in,
                              void* d_out, int out_size, void* d_ws, size_t ws_size,
                              hipStream_t stream)
{
    const void* x   = d_in[0];
    const void* spk = d_in[1];
    const void* emb = d_in[2];

    // per-chunk batch count: hi+lo f16 (= 4B/elem total) + e2 + partials + flag
    int Bc = 16;
    while (Bc > 1 && ((size_t)Bc*N_*D_*4 + (size_t)Bc*N_*4 + 4096 + 16) > ws_size) Bc >>= 1;

    char*  ws   = (char*)d_ws;
    f16*   hig  = (f16*)ws;                                      // Bc*512*256 f16
    f16*   logp = (f16*)(ws + (size_t)Bc*N_*D_*2);               // Bc*512*256 f16
    float* e2g  = (float*)(ws + (size_t)Bc*N_*D_*4);             // Bc*512 fp32
    float* part = (float*)(ws + (size_t)Bc*N_*D_*4 + (size_t)Bc*N_*4); // 1024 floats
    int*   flg  = (int*)((char*)part + 4096);                    // 4 B

    float* outf = (float*)d_out;

    hipMemsetAsync(part, 0, 4096, stream);
    k_probe<<<1, 64, 0, stream>>>((const ushortT*)x, flg);

    for (int b0 = 0; b0 < BTOT; b0 += Bc){
        switch (Bc){
            case 16: k_codebook<16><<<512, 256, 0, stream>>>(spk, emb, hig, logp, e2g, b0, flg); break;
            case 8:  k_codebook<8> <<<512, 256, 0, stream>>>(spk, emb, hig, logp, e2g, b0, flg); break;
            case 4:  k_codebook<4> <<<512, 256, 0, stream>>>(spk, emb, hig, logp, e2g, b0, flg); break;
            case 2:  k_codebook<2> <<<512, 256, 0, stream>>>(spk, emb, hig, logp, e2g, b0, flg); break;
            default: k_codebook<1> <<<512, 256, 0, stream>>>(spk, emb, hig, logp, e2g, b0, flg); break;
        }
        k_fused<<<Bc*32, 512, 0, stream>>>(x, hig, logp, e2g, outf, part, b0, flg);
    }
    k_fin<<<1, 256, 0, stream>>>(part, outf);
}

// Round 3
// 348.648 us; speedup vs baseline: 1.1070x; 1.0309x over previous
//
#include <hip/hip_runtime.h>

#define T_   2048
#define D_   256
#define N_   512
#define BTOT 16

typedef unsigned short ushortT;
typedef _Float16 f16;
typedef f16 h8 __attribute__((ext_vector_type(8)));
typedef float f4v __attribute__((ext_vector_type(4)));

// fp32 output layout (out_size = 8,421,377 floats):
//   [0, 8388608)  quantize (B,T,D) ; [8388608] diff ; [8388609, +B*T) indices
#define QN   ((size_t)BTOT*T_*D_)
#define IDX0 (QN + 1)
#define CBSTRIDE ((size_t)N_*D_)   // f16 elems per batch-slot in hi/lo

__device__ __forceinline__ float bf2f(ushortT u){
    union { unsigned int i; float f; } c; c.i = ((unsigned int)u) << 16; return c.f;
}
__device__ __forceinline__ void unp8(uint4 p, float* f){
    f[0]=bf2f((ushortT)(p.x & 0xffff)); f[1]=bf2f((ushortT)(p.x >> 16));
    f[2]=bf2f((ushortT)(p.y & 0xffff)); f[3]=bf2f((ushortT)(p.y >> 16));
    f[4]=bf2f((ushortT)(p.z & 0xffff)); f[5]=bf2f((ushortT)(p.z >> 16));
    f[6]=bf2f((ushortT)(p.w & 0xffff)); f[7]=bf2f((ushortT)(p.w >> 16));
}
__device__ __forceinline__ f4v mfma16(h8 a, h8 b, f4v c){
    return __builtin_amdgcn_mfma_f32_16x16x32_f16(a, b, c, 0, 0, 0);
}

// ---- dtype probe: bf16 vs fp32 input buffers ------------------------------
__global__ void k_probe(const ushortT* __restrict__ x, int* __restrict__ flg){
    int tid = threadIdx.x;
    ushortT u = x[tid];
    int e = (u >> 7) & 0xff;
    bool ok = (e >= 100 && e <= 140);
    unsigned long long m = __ballot(ok);
    if (tid == 0) *flg = (__popcll(m) >= 55) ? 1 : 0;
}

// ---- K1: codebook build, ALL 16 batches, ONE embedding read ---------------
// hi/lo f16 exact 2-term split (lo scaled 2^12) in MFMA 16x16x32 B-fragment
// order: elem(n,d) at ((n>>4)*8+(d>>5))*512 + ((d>>3)&3)*128 + (n&15)*8 + (d&7)
// batches 0..7  -> ws (hig/logp/e2g);  batches 8..15 -> stash in d_out.
__global__ __launch_bounds__(256) void k_codebook16(
    const void* __restrict__ spkin, const void* __restrict__ embin,
    f16* __restrict__ hig, f16* __restrict__ logp, float* __restrict__ e2g,
    f16* __restrict__ shi, f16* __restrict__ slo, float* __restrict__ se2,
    const int* __restrict__ flagp)
{
    const int isb = *flagp;
    const ushortT* ss = (const ushortT*)spkin;
    const float*   sf = (const float*)spkin;
    const ushortT* es = (const ushortT*)embin;
    const float*   ef = (const float*)embin;

    __shared__ float s2[D_ * 16];
    __shared__ float s1[D_ * 16];
    __shared__ float red[16 * D_];
    __shared__ float nrm[16];

    const int n = blockIdx.x, tid = threadIdx.x;

    for (int e = tid; e < D_ * 16; e += 256){
        int blc = e >> 8, k = e & 255;
        int g2 = (2*BTOT + blc)*D_ + k;
        int g1 = (1*BTOT + blc)*D_ + k;
        s2[k*16 + blc] = isb ? bf2f(ss[g2]) : sf[g2];
        s1[k*16 + blc] = isb ? bf2f(ss[g1]) : sf[g1];
    }
    __syncthreads();

    const int d = tid;
    float acc[16];
    #pragma unroll
    for (int b = 0; b < 16; b++) acc[b] = 0.f;

    const size_t rb = ((size_t)n * D_ + d) * D_;

    auto inner = [&](const float* ev, int k0){
        #pragma unroll
        for (int j = 0; j < 8; j++){
            float e = ev[j];
            const float4* sp = (const float4*)&s2[(k0 + j) * 16];
            float4 q0 = sp[0], q1 = sp[1], q2 = sp[2], q3 = sp[3];
            acc[0]  += e*q0.x; acc[1]  += e*q0.y; acc[2]  += e*q0.z; acc[3]  += e*q0.w;
            acc[4]  += e*q1.x; acc[5]  += e*q1.y; acc[6]  += e*q1.z; acc[7]  += e*q1.w;
            acc[8]  += e*q2.x; acc[9]  += e*q2.y; acc[10] += e*q2.z; acc[11] += e*q2.w;
            acc[12] += e*q3.x; acc[13] += e*q3.y; acc[14] += e*q3.z; acc[15] += e*q3.w;
        }
    };

    if (isb){
        for (int k0 = 0; k0 < D_; k0 += 8){
            uint4 p = *(const uint4*)(es + rb + k0);
            float ev[8]; unp8(p, ev);
            inner(ev, k0);
        }
    } else {
        for (int k0 = 0; k0 < D_; k0 += 8){
            float4 p0 = *(const float4*)(ef + rb + k0);
            float4 p1 = *(const float4*)(ef + rb + k0 + 4);
            float ev[8] = {p0.x,p0.y,p0.z,p0.w,p1.x,p1.y,p1.z,p1.w};
            inner(ev, k0);
        }
    }

    #pragma unroll
    for (int blc = 0; blc < 16; blc++) red[blc*D_ + d] = acc[blc]*acc[blc];
    __syncthreads();
    for (int s = 128; s > 0; s >>= 1){
        if (d < s){
            #pragma unroll
            for (int blc = 0; blc < 16; blc++) red[blc*D_ + d] += red[blc*D_ + d + s];
        }
        __syncthreads();
    }
    if (d < 16) nrm[d] = sqrtf(red[d*D_]);
    __syncthreads();

    float cbv[16];
    #pragma unroll
    for (int blc = 0; blc < 16; blc++)
        cbv[blc] = acc[blc] / nrm[blc] + s1[d*16 + blc];

    // e2 reduction (red free after nrm barrier)
    #pragma unroll
    for (int blc = 0; blc < 16; blc++) red[blc*D_ + d] = cbv[blc]*cbv[blc];
    __syncthreads();
    for (int s = 128; s > 0; s >>= 1){
        if (d < s){
            #pragma unroll
            for (int blc = 0; blc < 16; blc++) red[blc*D_ + d] += red[blc*D_ + d + s];
        }
        __syncthreads();
    }
    if (d < 16){
        float v = red[d*D_];
        if (d < 8) e2g[(size_t)d*N_ + n] = v;
        else       se2[(size_t)(d-8)*N_ + n] = v;
    }

    // exact f16 hi/lo split staged in s2 (free after inner loop): 8192 f16
    f16* sh = (f16*)s2;
    #pragma unroll
    for (int blc = 0; blc < 16; blc++){
        float c = cbv[blc];
        f16 h = (f16)c;
        float r = c - (float)h;     // exact in fp32
        f16 l = (f16)(r * 4096.f);  // 2^12 scale: exact, no f16 denorms
        sh[blc*256 + d] = h;
        sh[4096 + blc*256 + d] = l;
    }
    __syncthreads();
    // fragment-order 16B writes, dual destination
    for (int w = tid; w < 16*32; w += 256){
        const int blc = w >> 5, g = w & 31;
        const int d0 = (g>>2)*32 + (g&3)*8;
        const size_t off = (size_t)(blc & 7)*CBSTRIDE
                         + (size_t)((n>>4)*8 + (g>>2))*512
                         + (size_t)(g&3)*128 + (size_t)(n&15)*8;
        f16* dh = (blc < 8) ? hig  : shi;
        f16* dl = (blc < 8) ? logp : slo;
        *(uint4*)(dh + off) = *(const uint4*)(sh + blc*256 + d0);
        *(uint4*)(dl + off) = *(const uint4*)(sh + 4096 + blc*256 + d0);
    }
}

// ---- K2: fused scores GEMM (MFMA hi/lo) + argmin + gather + diff ----------
// grid 512 blocks: bl = bid&7 (XCD-local codebook), tT = bid>>3 (64 tiles).
// 256 threads = 4 waves = 2 row-bands x 2 N-halves; 32 rows per block.
// A resident in regs; B ping-pong prefetched from L2. No LDS in main loop.
__global__ __launch_bounds__(256, 2) void k_fused(
    const void* __restrict__ xin,
    const f16* __restrict__ hig, const f16* __restrict__ logp,
    const float* __restrict__ e2g,
    float* __restrict__ outf, float* __restrict__ part,
    int blk0, const int* __restrict__ flagp)
{
    __shared__ float mv[4 * 16];
    __shared__ int   mi[4 * 16];
    __shared__ int   sfin[32];
    __shared__ float wsum[4];

    const int isb = *flagp;
    const int tid = threadIdx.x;
    const int bl = blockIdx.x & 7, tT = blockIdx.x >> 3;
    const int bg = blk0 + bl;
    const int lane = tid & 63, wid = tid >> 6;
    const int band = wid >> 1, nh = wid & 1;
    const int arow = lane & 15, kgrp = lane >> 4;

    const ushortT* xs = (const ushortT*)xin;
    const float*   xf = (const float*)xin;

    // ---- A fragments: 16 rows x K=256, exact hi/lo f16 split --------------
    h8 ah[8], al[8];
    {
        const size_t rowbase = ((size_t)bg*T_ + (size_t)tT*32 + band*16 + arow) * D_;
        #pragma unroll
        for (int ks = 0; ks < 8; ks++){
            float f[8];
            const size_t o = rowbase + ks*32 + kgrp*8;
            if (isb){
                uint4 p = *(const uint4*)(xs + o);
                unp8(p, f);
            } else {
                float4 p0 = *(const float4*)(xf + o);
                float4 p1 = *(const float4*)(xf + o + 4);
                f[0]=p0.x; f[1]=p0.y; f[2]=p0.z; f[3]=p0.w;
                f[4]=p1.x; f[5]=p1.y; f[6]=p1.z; f[7]=p1.w;
            }
            h8 h, l;
            #pragma unroll
            for (int j = 0; j < 8; j++){
                f16 hh = (f16)f[j];
                h[j] = hh;
                l[j] = (f16)((f[j] - (float)hh) * 4096.f);  // exact residual
            }
            ah[ks] = h; al[ks] = l;
        }
    }

    const f16* hb = hig  + (size_t)bl*CBSTRIDE + (size_t)(lane*8);
    const f16* lb = logp + (size_t)bl*CBSTRIDE + (size_t)(lane*8);
    const float* e2b = e2g + (size_t)bl*N_;

    float runv[4]; int runi[4];
    #pragma unroll
    for (int i = 0; i < 4; i++){ runv[i] = 3.4e38f; runi[i] = 0x7fffffff; }

    // ping-pong B fragment registers
    h8 a0h, a1h, a0l, a1l;     // buffer A
    h8 b0h, b1h, b0l, b1l;     // buffer B

    const f16* hc = hb + (size_t)(nh*16)*4096;
    const f16* lc = lb + (size_t)(nh*16)*4096;

    // initial load: (c=0, ks=0)
    a0h = *(const h8*)(hc);          a1h = *(const h8*)(hc + 4096);
    a0l = *(const h8*)(lc);          a1l = *(const h8*)(lc + 4096);

    f4v acch0, acch1, accm0, accm1, accl0, accl1;

    #pragma unroll 1
    for (int c = 0; c < 8; c++){
        acch0 = (f4v){0.f,0.f,0.f,0.f}; acch1 = acch0;
        accm0 = acch0; accm1 = acch0; accl0 = acch0; accl1 = acch0;

        #pragma unroll
        for (int ks2 = 0; ks2 < 4; ks2++){
            const int ks = ks2*2;
            // prefetch ks+1 into buffer B
            {
                const f16* h2 = hc + (ks+1)*512;
                const f16* l2 = lc + (ks+1)*512;
                b0h = *(const h8*)(h2);       b1h = *(const h8*)(h2 + 4096);
                b0l = *(const h8*)(l2);       b1l = *(const h8*)(l2 + 4096);
            }
            // compute ks from buffer A (same-acc ops 4 apart)
            acch0 = mfma16(ah[ks], a0h, acch0);
            acch1 = mfma16(ah[ks], a1h, acch1);
            accm0 = mfma16(ah[ks], a0l, accm0);
            accm1 = mfma16(ah[ks], a1l, accm1);
            accl0 = mfma16(al[ks], a0l, accl0);
            accl1 = mfma16(al[ks], a1l, accl1);
            accm0 = mfma16(al[ks], a0h, accm0);
            accm1 = mfma16(al[ks], a1h, accm1);
            // prefetch ks+2 (or next c's ks=0) into buffer A
            if (ks2 < 3){
                const f16* h2 = hc + (ks+2)*512;
                const f16* l2 = lc + (ks+2)*512;
                a0h = *(const h8*)(h2);       a1h = *(const h8*)(h2 + 4096);
                a0l = *(const h8*)(l2);       a1l = *(const h8*)(l2 + 4096);
            } else if (c < 7){
                const f16* h2 = hc + 8192;
                const f16* l2 = lc + 8192;
                a0h = *(const h8*)(h2);       a1h = *(const h8*)(h2 + 4096);
                a0l = *(const h8*)(l2);       a1l = *(const h8*)(l2 + 4096);
            }
            // compute ks+1 from buffer B
            acch0 = mfma16(ah[ks+1], b0h, acch0);
            acch1 = mfma16(ah[ks+1], b1h, acch1);
            accm0 = mfma16(ah[ks+1], b0l, accm0);
            accm1 = mfma16(ah[ks+1], b1l, accm1);
            accl0 = mfma16(al[ks+1], b0l, accl0);
            accl1 = mfma16(al[ks+1], b1l, accl1);
            accm0 = mfma16(al[ks+1], b0h, accm0);
            accm1 = mfma16(al[ks+1], b1h, accm1);
        }

        // scores: lane owns rows m = kgrp*4 + r, cols nn0 / nn0+16
        {
            const int nn0 = (nh*16 + c*2)*16 + arow;
            const float e20 = e2b[nn0], e21 = e2b[nn0 + 16];
            #pragma unroll
            for (int r = 0; r < 4; r++){
                float d0 = acch0[r] + accm0[r]*(1.f/4096.f) + accl0[r]*(1.f/16777216.f);
                float s0 = e20 - 2.f*d0;
                if (s0 < runv[r]){ runv[r] = s0; runi[r] = nn0; }
                float d1 = acch1[r] + accm1[r]*(1.f/4096.f) + accl1[r]*(1.f/16777216.f);
                float s1 = e21 - 2.f*d1;
                if (s1 < runv[r]){ runv[r] = s1; runi[r] = nn0 + 16; }
            }
        }
        hc += 8192; lc += 8192;
    }

    // argmin across the 16 arow-lanes (xor masks stay within the 16-group)
    #pragma unroll
    for (int m = 8; m >= 1; m >>= 1){
        #pragma unroll
        for (int r = 0; r < 4; r++){
            float ov = __shfl_xor(runv[r], m);
            int   on = __shfl_xor(runi[r], m);
            if (ov < runv[r] || (ov == runv[r] && on < runi[r])){
                runv[r] = ov; runi[r] = on;
            }
        }
    }
    if (arow == 0){
        #pragma unroll
        for (int r = 0; r < 4; r++){
            mv[wid*16 + kgrp*4 + r] = runv[r];
            mi[wid*16 + kgrp*4 + r] = runi[r];
        }
    }
    __syncthreads();
    if (tid < 32){
        const int bandt = tid >> 4, rl = tid & 15;
        float v0 = mv[(bandt*2    )*16 + rl]; int i0 = mi[(bandt*2    )*16 + rl];
        float v1 = mv[(bandt*2 + 1)*16 + rl]; int i1 = mi[(bandt*2 + 1)*16 + rl];
        int nf = (v1 < v0) ? i1 : i0;          // strict: nh=0 wins ties (lower n)
        sfin[tid] = nf;
        outf[IDX0 + (size_t)bg*T_ + (size_t)tT*32 + tid] = (float)nf;
    }
    __syncthreads();

    // ---- fused gather + quantize write + diff partials --------------------
    // thread: row r = tid>>3 (32 rows), d-octant oct = tid&7 (32 d each)
    float dacc = 0.f;
    {
        const int r = tid >> 3, oct = tid & 7;
        const int nn = sfin[r];
        const size_t fb = (size_t)bl*CBSTRIDE
                        + (size_t)((nn>>4)*8 + oct)*512 + (size_t)(nn&15)*8;
        const size_t xo0 = ((size_t)bg*T_ + (size_t)tT*32 + r)*D_ + oct*32;
        #pragma unroll
        for (int q = 0; q < 4; q++){
            h8 hq = *(const h8*)(hig  + fb + q*128);
            h8 lq = *(const h8*)(logp + fb + q*128);
            float xv[8];
            if (isb){
                uint4 p = *(const uint4*)(xs + xo0 + q*8);
                unp8(p, xv);
            } else {
                float4 p0 = *(const float4*)(xf + xo0 + q*8);
                float4 p1 = *(const float4*)(xf + xo0 + q*8 + 4);
                xv[0]=p0.x; xv[1]=p0.y; xv[2]=p0.z; xv[3]=p0.w;
                xv[4]=p1.x; xv[5]=p1.y; xv[6]=p1.z; xv[7]=p1.w;
            }
            float og[8];
            #pragma unroll
            for (int j = 0; j < 8; j++){
                float qv = (float)hq[j] + (float)lq[j]*(1.f/4096.f);
                float qm = qv - xv[j];
                dacc += qm*qm;
                og[j] = 0.5f*(qv + (xv[j] + qm));
            }
            *(float4*)(outf + xo0 + q*8)     = make_float4(og[0],og[1],og[2],og[3]);
            *(float4*)(outf + xo0 + q*8 + 4) = make_float4(og[4],og[5],og[6],og[7]);
        }
    }
    #pragma unroll
    for (int o2 = 32; o2 > 0; o2 >>= 1) dacc += __shfl_down(dacc, o2, 64);
    if (lane == 0) wsum[wid] = dacc;
    __syncthreads();
    if (tid == 0){
        float t = wsum[0] + wsum[1] + wsum[2] + wsum[3];
        atomicAdd(&part[blockIdx.x & 1023], t);
    }
}

// ---- K4: finalize diff (sum 1024 partials) --------------------------------
__global__ __launch_bounds__(256) void k_fin(const float* __restrict__ part,
                                             float* __restrict__ outf){
    const int tid = threadIdx.x;
    float v = part[tid] + part[tid + 256] + part[tid + 512] + part[tid + 768];
    #pragma unroll
    for (int o = 32; o > 0; o >>= 1) v += __shfl_down(v, o, 64);
    __shared__ float wsum[4];
    if ((tid & 63) == 0) wsum[tid >> 6] = v;
    __syncthreads();
    if (tid == 0)
        outf[QN] = (wsum[0] + wsum[1] + wsum[2] + wsum[3]) * (1.0f / (float)QN);
}

extern "C" void kernel_launch(void* const* d_in, const int* in_sizes, int n_in,
                              void* d_out, int out_size, void* d_ws, size_t ws_size,
                              hipStream_t stream)
{
    const void* x   = d_in[0];
    const void* spk = d_in[1];
    const void* emb = d_in[2];

    float* outf = (float*)d_out;

    // ws layout (identical footprint to the proven Bc=8 layout):
    //   hig (2MB) | logp (2MB) | e2g (16KB) | part (4KB) | flg
    char*  ws   = (char*)d_ws;
    f16*   hig  = (f16*)ws;
    f16*   logp = (f16*)(ws + (size_t)8*N_*D_*2);
    float* e2g  = (float*)(ws + (size_t)8*N_*D_*4);
    float* part = (float*)(ws + (size_t)8*N_*D_*4 + (size_t)8*N_*4);
    int*   flg  = (int*)((char*)part + 4096);

    // stash for batches 8..15 in d_out's batch-0..7 quantize region
    // (written by codebook, consumed by fused(b0=8), overwritten by fused(b0=0))
    f16*   shi = (f16*)outf;                   // 1,048,576 f16 = 2MB
    f16*   slo = (f16*)(outf + 524288);        // 2MB
    float* se2 = outf + 1048576;               // 16KB

    hipMemsetAsync(part, 0, 4096, stream);
    k_probe<<<1, 64, 0, stream>>>((const ushortT*)x, flg);

    k_codebook16<<<512, 256, 0, stream>>>(spk, emb, hig, logp, e2g,
                                          shi, slo, se2, flg);
    k_fused<<<512, 256, 0, stream>>>(x, shi, slo, se2, outf, part, 8, flg);
    k_fused<<<512, 256, 0, stream>>>(x, hig, logp, e2g, outf, part, 0, flg);
    k_fin<<<1, 256, 0, stream>>>(part, outf);
}

// Round 4
// 333.924 us; speedup vs baseline: 1.1559x; 1.0441x over previous
//
#include <hip/hip_runtime.h>

#define T_   2048
#define D_   256
#define N_   512
#define BTOT 16

typedef unsigned short ushortT;
typedef _Float16 f16;
typedef f16 h8 __attribute__((ext_vector_type(8)));
typedef float f4v __attribute__((ext_vector_type(4)));

// fp32 output layout (out_size = 8,421,377 floats):
//   [0, 8388608)  quantize (B,T,D) ; [8388608] diff ; [8388609, +B*T) indices
#define QN   ((size_t)BTOT*T_*D_)
#define IDX0 (QN + 1)
#define CBSTRIDE ((size_t)N_*D_)   // f16 elems per batch-slot in hi/lo

__device__ __forceinline__ float bf2f(ushortT u){
    union { unsigned int i; float f; } c; c.i = ((unsigned int)u) << 16; return c.f;
}
__device__ __forceinline__ void unp8(uint4 p, float* f){
    f[0]=bf2f((ushortT)(p.x & 0xffff)); f[1]=bf2f((ushortT)(p.x >> 16));
    f[2]=bf2f((ushortT)(p.y & 0xffff)); f[3]=bf2f((ushortT)(p.y >> 16));
    f[4]=bf2f((ushortT)(p.z & 0xffff)); f[5]=bf2f((ushortT)(p.z >> 16));
    f[6]=bf2f((ushortT)(p.w & 0xffff)); f[7]=bf2f((ushortT)(p.w >> 16));
}
__device__ __forceinline__ void unp4(uint2 p, float* f){
    f[0]=bf2f((ushortT)(p.x & 0xffff)); f[1]=bf2f((ushortT)(p.x >> 16));
    f[2]=bf2f((ushortT)(p.y & 0xffff)); f[3]=bf2f((ushortT)(p.y >> 16));
}
__device__ __forceinline__ f4v mfma16(h8 a, h8 b, f4v c){
    return __builtin_amdgcn_mfma_f32_16x16x32_f16(a, b, c, 0, 0, 0);
}

// ---- dtype probe: bf16 vs fp32 input buffers ------------------------------
__global__ void k_probe(const ushortT* __restrict__ x, int* __restrict__ flg){
    int tid = threadIdx.x;
    ushortT u = x[tid];
    int e = (u >> 7) & 0xff;
    bool ok = (e >= 100 && e <= 140);
    unsigned long long m = __ballot(ok);
    if (tid == 0) *flg = (__popcll(m) >= 55) ? 1 : 0;
}

// ---- K1: codebook build, ALL 16 batches, ONE coalesced embedding read -----
// hi/lo f16 exact 2-term split (lo scaled 2^12) in MFMA 16x16x32 B-fragment
// order: elem(n,d) at ((n>>4)*8+(d>>5))*512 + ((d>>3)&3)*128 + (n&15)*8 + (d&7)
// batches 0..7 -> ws; batches 8..15 -> stash in d_out.
__global__ __launch_bounds__(256) void k_codebook16(
    const void* __restrict__ spkin, const void* __restrict__ embin,
    f16* __restrict__ hig, f16* __restrict__ logp, float* __restrict__ e2g,
    f16* __restrict__ shi, f16* __restrict__ slo, float* __restrict__ se2,
    const int* __restrict__ flagp)
{
    const int isb = *flagp;
    const ushortT* ss = (const ushortT*)spkin;
    const float*   sf = (const float*)spkin;
    const ushortT* es = (const ushortT*)embin;
    const float*   ef = (const float*)embin;

    __shared__ float s2[D_ * 16];     // [k][16] mul
    __shared__ float s1[D_ * 16];     // [k][16] add
    __shared__ float tile[256 * 32];  // 32KB k-chunk tile, XOR-swizzled; red aliases
    __shared__ float nrm[16];
    float* red = tile;

    const int n = blockIdx.x, tid = threadIdx.x;

    // conflict-free s1/s2 staging: addr = e (consecutive), k=e>>4, blc=e&15
    for (int e = tid; e < D_ * 16; e += 256){
        int k = e >> 4, blc = e & 15;
        int g2 = (2*BTOT + blc)*D_ + k;
        int g1 = (1*BTOT + blc)*D_ + k;
        s2[e] = isb ? bf2f(ss[g2]) : sf[g2];
        s1[e] = isb ? bf2f(ss[g1]) : sf[g1];
    }

    const int d = tid;
    float acc[16];
    #pragma unroll
    for (int b = 0; b < 16; b++) acc[b] = 0.f;

    // register-staged coalesced chunk loads (8 chunks of 32 k)
    float4 st[8];     // fp32 path: 8 rounds x (row=r8*32+tid>>3, q=tid&7)
    uint4  st4[4];    // bf16 path: 4 rounds x (row=r4*64+tid>>2, q=tid&3)

    const size_t embbase = (size_t)n * D_ * D_;

    auto loadF = [&](int kc){
        #pragma unroll
        for (int r8 = 0; r8 < 8; r8++){
            int row = r8*32 + (tid>>3);
            st[r8] = *(const float4*)(ef + embbase + (size_t)row*D_ + kc + (tid&7)*4);
        }
    };
    auto writeF = [&](){
        #pragma unroll
        for (int r8 = 0; r8 < 8; r8++){
            int row = r8*32 + (tid>>3);
            int idx = (row*32 + (tid&7)*4) ^ ((row&7)<<2);
            *(float4*)&tile[idx] = st[r8];
        }
    };
    auto loadB = [&](int kc){
        #pragma unroll
        for (int r4 = 0; r4 < 4; r4++){
            int row = r4*64 + (tid>>2);
            st4[r4] = *(const uint4*)(es + embbase + (size_t)row*D_ + kc + (tid&3)*8);
        }
    };
    auto writeB = [&](){
        #pragma unroll
        for (int r4 = 0; r4 < 4; r4++){
            int row = r4*64 + (tid>>2);
            float f[8]; unp8(st4[r4], f);
            int i0 = (row*32 + (tid&3)*8) ^ ((row&7)<<2);
            int i1 = (row*32 + (tid&3)*8 + 4) ^ ((row&7)<<2);
            *(float4*)&tile[i0] = make_float4(f[0],f[1],f[2],f[3]);
            *(float4*)&tile[i1] = make_float4(f[4],f[5],f[6],f[7]);
        }
    };

    if (isb) loadB(0); else loadF(0);

    #pragma unroll 1
    for (int c8 = 0; c8 < 8; c8++){
        __syncthreads();                         // prev compute done / s1-s2 staged
        if (isb) writeB(); else writeF();
        __syncthreads();
        if (c8 < 7){ if (isb) loadB((c8+1)*32); else loadF((c8+1)*32); }
        // compute chunk c8: thread d consumes its row's 32 k values
        #pragma unroll
        for (int j2 = 0; j2 < 8; j2++){
            int idx = (d*32 + j2*4) ^ ((d&7)<<2);
            float4 ev = *(const float4*)&tile[idx];
            float evs[4] = {ev.x, ev.y, ev.z, ev.w};
            #pragma unroll
            for (int jj = 0; jj < 4; jj++){
                float e = evs[jj];
                const float4* sp = (const float4*)&s2[(c8*32 + j2*4 + jj) * 16];
                float4 q0 = sp[0], q1 = sp[1], q2 = sp[2], q3 = sp[3];
                acc[0]  += e*q0.x; acc[1]  += e*q0.y; acc[2]  += e*q0.z; acc[3]  += e*q0.w;
                acc[4]  += e*q1.x; acc[5]  += e*q1.y; acc[6]  += e*q1.z; acc[7]  += e*q1.w;
                acc[8]  += e*q2.x; acc[9]  += e*q2.y; acc[10] += e*q2.z; acc[11] += e*q2.w;
                acc[12] += e*q3.x; acc[13] += e*q3.y; acc[14] += e*q3.z; acc[15] += e*q3.w;
            }
        }
    }
    __syncthreads();   // tile dead; red alias begins

    #pragma unroll
    for (int blc = 0; blc < 16; blc++) red[blc*D_ + d] = acc[blc]*acc[blc];
    __syncthreads();
    for (int s = 128; s > 0; s >>= 1){
        if (d < s){
            #pragma unroll
            for (int blc = 0; blc < 16; blc++) red[blc*D_ + d] += red[blc*D_ + d + s];
        }
        __syncthreads();
    }
    if (d < 16) nrm[d] = sqrtf(red[d*D_]);
    __syncthreads();

    float cbv[16];
    #pragma unroll
    for (int blc = 0; blc < 16; blc++)
        cbv[blc] = acc[blc] / nrm[blc] + s1[d*16 + blc];

    // e2 reduction
    #pragma unroll
    for (int blc = 0; blc < 16; blc++) red[blc*D_ + d] = cbv[blc]*cbv[blc];
    __syncthreads();
    for (int s = 128; s > 0; s >>= 1){
        if (d < s){
            #pragma unroll
            for (int blc = 0; blc < 16; blc++) red[blc*D_ + d] += red[blc*D_ + d + s];
        }
        __syncthreads();
    }
    if (d < 16){
        float v = red[d*D_];
        if (d < 8) e2g[(size_t)d*N_ + n] = v;
        else       se2[(size_t)(d-8)*N_ + n] = v;
    }

    // exact f16 hi/lo split staged in s2 (free now): 8192 f16
    f16* sh = (f16*)s2;
    #pragma unroll
    for (int blc = 0; blc < 16; blc++){
        float c = cbv[blc];
        f16 h = (f16)c;
        float r = c - (float)h;     // exact in fp32
        f16 l = (f16)(r * 4096.f);  // 2^12 scale: exact, no f16 denorms
        sh[blc*256 + d] = h;
        sh[4096 + blc*256 + d] = l;
    }
    __syncthreads();
    // fragment-order 16B writes, dual destination
    for (int w = tid; w < 16*32; w += 256){
        const int blc = w >> 5, g = w & 31;
        const int d0 = (g>>2)*32 + (g&3)*8;
        const size_t off = (size_t)(blc & 7)*CBSTRIDE
                         + (size_t)((n>>4)*8 + (g>>2))*512
                         + (size_t)(g&3)*128 + (size_t)(n&15)*8;
        f16* dh = (blc < 8) ? hig  : shi;
        f16* dl = (blc < 8) ? logp : slo;
        *(uint4*)(dh + off) = *(const uint4*)(sh + blc*256 + d0);
        *(uint4*)(dl + off) = *(const uint4*)(sh + 4096 + blc*256 + d0);
    }
}

// ---- K2: fused scores GEMM (MFMA hi/lo) + argmin + gather + diff ----------
// grid 256 blocks: bl = bid&7 (XCD-local codebook), tT = bid>>3 (32 tiles).
// 512 threads = 8 waves = 4 row-bands x 2 N-halves; 64 rows per block.
// x staged coalesced into LDS (also feeds gather); B depth-3 reg-prefetched.
#define ISSUE(cc, kss, slot) do{                                   \
    const f16* hc_ = hb + (size_t)(cc)*8192;                       \
    const f16* lc_ = lb + (size_t)(cc)*8192;                       \
    bh0[slot] = *(const h8*)(hc_ + (kss)*512);                     \
    bh1[slot] = *(const h8*)(hc_ + 4096 + (kss)*512);              \
    bl0[slot] = *(const h8*)(lc_ + (kss)*512);                     \
    bl1[slot] = *(const h8*)(lc_ + 4096 + (kss)*512);              \
}while(0)

__global__ __launch_bounds__(512, 2) void k_fused(
    const void* __restrict__ xin,
    const f16* __restrict__ hig, const f16* __restrict__ logp,
    const float* __restrict__ e2g,
    float* __restrict__ outf, float* __restrict__ part,
    int blk0, const int* __restrict__ flagp)
{
    __shared__ float xt[64 * 256];    // 64KB x tile, row-XOR-swizzled
    __shared__ float mv[8 * 16];
    __shared__ int   mi[8 * 16];
    __shared__ int   sfin[64];
    __shared__ float wsum[8];

    const int isb = *flagp;
    const int tid = threadIdx.x;
    const int bl = blockIdx.x & 7, tT = blockIdx.x >> 3;
    const int bg = blk0 + bl;
    const int lane = tid & 63, wid = tid >> 6;
    const int band = wid >> 1, nh = wid & 1;
    const int arow = lane & 15, kgrp = lane >> 4;

    const f16* hb = hig  + (size_t)bl*CBSTRIDE + (size_t)(nh*16)*4096 + (size_t)lane*8;
    const f16* lb = logp + (size_t)bl*CBSTRIDE + (size_t)(nh*16)*4096 + (size_t)lane*8;
    const float* e2b = e2g + (size_t)bl*N_;

    // early B prefetch (hides L2 latency under x staging)
    h8 bh0[4], bh1[4], bl0[4], bl1[4];
    ISSUE(0, 0, 0); ISSUE(0, 1, 1); ISSUE(0, 2, 2);

    // ---- stage x tile: 64 rows, one full coalesced row per wave-instr -----
    const size_t xrow0 = (size_t)bg*T_ + (size_t)tT*64;
    if (isb){
        const ushortT* xs = (const ushortT*)xin;
        #pragma unroll
        for (int it = 0; it < 8; it++){
            int r = it*8 + wid;
            uint2 p = *(const uint2*)(xs + (xrow0 + r)*D_ + lane*4);
            float f[4]; unp4(p, f);
            int idx = (r*256 + lane*4) ^ ((r&7)<<2);
            *(float4*)&xt[idx] = make_float4(f[0],f[1],f[2],f[3]);
        }
    } else {
        const float* xf = (const float*)xin;
        #pragma unroll
        for (int it = 0; it < 8; it++){
            int r = it*8 + wid;
            float4 p = *(const float4*)(xf + (xrow0 + r)*D_ + lane*4);
            int idx = (r*256 + lane*4) ^ ((r&7)<<2);
            *(float4*)&xt[idx] = p;
        }
    }
    __syncthreads();

    // ---- A fragments from LDS: 16 rows x K=256, exact hi/lo f16 split -----
    h8 ah[8], al[8];
    {
        const int rr = band*16 + arow;
        const int sw = (rr&7)<<2;
        #pragma unroll
        for (int ks = 0; ks < 8; ks++){
            int base = rr*256 + ks*32 + kgrp*8;
            float4 f0 = *(const float4*)&xt[(base    ) ^ sw];
            float4 f1 = *(const float4*)&xt[(base + 4) ^ sw];
            float f[8] = {f0.x,f0.y,f0.z,f0.w,f1.x,f1.y,f1.z,f1.w};
            h8 h, l;
            #pragma unroll
            for (int j = 0; j < 8; j++){
                f16 hh = (f16)f[j];
                h[j] = hh;
                l[j] = (f16)((f[j] - (float)hh) * 4096.f);
            }
            ah[ks] = h; al[ks] = l;
        }
    }

    float runv[4]; int runi[4];
    #pragma unroll
    for (int i = 0; i < 4; i++){ runv[i] = 3.4e38f; runi[i] = 0x7fffffff; }

    #pragma unroll 1
    for (int c = 0; c < 8; c++){
        f4v a0 = (f4v){0.f,0.f,0.f,0.f}, a1 = a0, m0 = a0, m1 = a0;
        #pragma unroll
        for (int ks = 0; ks < 8; ks++){
            if (ks < 5)      { ISSUE(c,   ks+3, (ks+3)&3); }
            else if (c < 7)  { ISSUE(c+1, ks-5, (ks+3)&3); }
            a0 = mfma16(ah[ks], bh0[ks&3], a0);
            a1 = mfma16(ah[ks], bh1[ks&3], a1);
            m0 = mfma16(ah[ks], bl0[ks&3], m0);
            m1 = mfma16(ah[ks], bl1[ks&3], m1);
            m0 = mfma16(al[ks], bh0[ks&3], m0);
            m1 = mfma16(al[ks], bh1[ks&3], m1);
        }
        const int nn0 = (nh*16 + c*2)*16 + arow;
        const float e20 = e2b[nn0], e21 = e2b[nn0 + 16];
        #pragma unroll
        for (int r = 0; r < 4; r++){
            float s0 = e20 - 2.f*(a0[r] + m0[r]*(1.f/4096.f));
            if (s0 < runv[r]){ runv[r] = s0; runi[r] = nn0; }
            float s1 = e21 - 2.f*(a1[r] + m1[r]*(1.f/4096.f));
            if (s1 < runv[r]){ runv[r] = s1; runi[r] = nn0 + 16; }
        }
    }

    // argmin across the 16 arow-lanes
    #pragma unroll
    for (int m = 8; m >= 1; m >>= 1){
        #pragma unroll
        for (int r = 0; r < 4; r++){
            float ov = __shfl_xor(runv[r], m);
            int   on = __shfl_xor(runi[r], m);
            if (ov < runv[r] || (ov == runv[r] && on < runi[r])){
                runv[r] = ov; runi[r] = on;
            }
        }
    }
    if (arow == 0){
        #pragma unroll
        for (int r = 0; r < 4; r++){
            mv[wid*16 + kgrp*4 + r] = runv[r];
            mi[wid*16 + kgrp*4 + r] = runi[r];
        }
    }
    __syncthreads();
    if (tid < 64){
        const int bandt = tid >> 4, rl = tid & 15;
        float v0 = mv[(bandt*2    )*16 + rl]; int i0 = mi[(bandt*2    )*16 + rl];
        float v1 = mv[(bandt*2 + 1)*16 + rl]; int i1 = mi[(bandt*2 + 1)*16 + rl];
        int nf = (v1 < v0) ? i1 : i0;          // strict: nh=0 wins ties (lower n)
        sfin[tid] = nf;
        outf[IDX0 + (size_t)bg*T_ + (size_t)tT*64 + tid] = (float)nf;
    }
    __syncthreads();

    // ---- fused gather + quantize write + diff (x from LDS tile) -----------
    float dacc = 0.f;
    {
        const int r = tid >> 3, oct = tid & 7;
        const int sw = (r&7)<<2;
        const int nn = sfin[r];
        const size_t fb = (size_t)bl*CBSTRIDE
                        + (size_t)((nn>>4)*8 + oct)*512 + (size_t)(nn&15)*8;
        const size_t xo0 = ((size_t)bg*T_ + (size_t)tT*64 + r)*D_ + oct*32;
        #pragma unroll
        for (int q = 0; q < 4; q++){
            h8 hq = *(const h8*)(hig  + fb + q*128);
            h8 lq = *(const h8*)(logp + fb + q*128);
            int xb = r*256 + oct*32 + q*8;
            float4 x0 = *(const float4*)&xt[(xb    ) ^ sw];
            float4 x1 = *(const float4*)&xt[(xb + 4) ^ sw];
            float xv[8] = {x0.x,x0.y,x0.z,x0.w,x1.x,x1.y,x1.z,x1.w};
            float og[8];
            #pragma unroll
            for (int j = 0; j < 8; j++){
                float qv = (float)hq[j] + (float)lq[j]*(1.f/4096.f);
                float qm = qv - xv[j];
                dacc += qm*qm;
                og[j] = 0.5f*(qv + (xv[j] + qm));
            }
            *(float4*)(outf + xo0 + q*8)     = make_float4(og[0],og[1],og[2],og[3]);
            *(float4*)(outf + xo0 + q*8 + 4) = make_float4(og[4],og[5],og[6],og[7]);
        }
    }
    #pragma unroll
    for (int o2 = 32; o2 > 0; o2 >>= 1) dacc += __shfl_down(dacc, o2, 64);
    if (lane == 0) wsum[wid] = dacc;
    __syncthreads();
    if (tid == 0){
        float t = 0.f;
        #pragma unroll
        for (int i = 0; i < 8; i++) t += wsum[i];
        atomicAdd(&part[blockIdx.x & 1023], t);
    }
}
#undef ISSUE

// ---- K4: finalize diff (sum 1024 partials) --------------------------------
__global__ __launch_bounds__(256) void k_fin(const float* __restrict__ part,
                                             float* __restrict__ outf){
    const int tid = threadIdx.x;
    float v = part[tid] + part[tid + 256] + part[tid + 512] + part[tid + 768];
    #pragma unroll
    for (int o = 32; o > 0; o >>= 1) v += __shfl_down(v, o, 64);
    __shared__ float wsum[4];
    if ((tid & 63) == 0) wsum[tid >> 6] = v;
    __syncthreads();
    if (tid == 0)
        outf[QN] = (wsum[0] + wsum[1] + wsum[2] + wsum[3]) * (1.0f / (float)QN);
}

extern "C" void kernel_launch(void* const* d_in, const int* in_sizes, int n_in,
                              void* d_out, int out_size, void* d_ws, size_t ws_size,
                              hipStream_t stream)
{
    const void* x   = d_in[0];
    const void* spk = d_in[1];
    const void* emb = d_in[2];

    float* outf = (float*)d_out;

    // ws layout: hig (2MB) | logp (2MB) | e2g (16KB) | part (4KB) | flg
    char*  ws   = (char*)d_ws;
    f16*   hig  = (f16*)ws;
    f16*   logp = (f16*)(ws + (size_t)8*N_*D_*2);
    float* e2g  = (float*)(ws + (size_t)8*N_*D_*4);
    float* part = (float*)(ws + (size_t)8*N_*D_*4 + (size_t)8*N_*4);
    int*   flg  = (int*)((char*)part + 4096);

    // stash for batches 8..15 in d_out's batch-0..2 quantize region
    // (written by codebook, consumed by fused(blk0=8), overwritten by fused(blk0=0))
    f16*   shi = (f16*)outf;                   // 2MB
    f16*   slo = (f16*)(outf + 524288);        // 2MB
    float* se2 = outf + 1048576;               // 16KB

    hipMemsetAsync(part, 0, 4096, stream);
    k_probe<<<1, 64, 0, stream>>>((const ushortT*)x, flg);

    k_codebook16<<<512, 256, 0, stream>>>(spk, emb, hig, logp, e2g,
                                          shi, slo, se2, flg);
    k_fused<<<256, 512, 0, stream>>>(x, shi, slo, se2, outf, part, 8, flg);
    k_fused<<<256, 512, 0, stream>>>(x, hig, logp, e2g, outf, part, 0, flg);
    k_fin<<<1, 256, 0, stream>>>(part, outf);
}